// Round 1
// baseline (211.656 us; speedup 1.0000x reference)
//
#include <hip/hip_runtime.h>

// Problem constants (fixed by the reference)
#define B_TOT   16384
#define N_CAP   32
#define J_CAP   16
#define I_DIM   8
#define D_DIM   16
#define TB      32      // b's per block
#define NTHREADS 256

// fp32 -> bf16 (RNE) and back, on raw bits
__device__ __forceinline__ unsigned short f2bf(float f) {
    unsigned int u = __float_as_uint(f);
    unsigned int r = (u + 0x7fffu + ((u >> 16) & 1u)) >> 16;
    return (unsigned short)r;
}
__device__ __forceinline__ float bf2f(unsigned int s) {   // s must be < 65536
    return __uint_as_float(s << 16);
}

__global__ __launch_bounds__(NTHREADS, 2)
void caps_fused(const float* __restrict__ X,     // (B, J, I)
                const float* __restrict__ W,     // (N, J, I, D)
                const float* __restrict__ Bias,  // (N, J, 1)
                float* __restrict__ Out)         // (B, N, D)
{
    // LDS budget: 8448 + 33792 + 2176 + 18560 + 2176 = 65152 B  (2 blocks/CU)
    __shared__ __align__(16) float sW[16 * 132];   // W[n] tile, j-row stride 132 dwords (conflict-free f4 reads)
    __shared__ unsigned short sC[32 * 528];        // logits -> c, bf16, [b]*528 + n*16 + j
    __shared__ float sBias[544];                   // [n]*17 + j
    __shared__ unsigned int sU[4640];              // u bf16 z-pairs, [b]*145 + j*9 + zp
    __shared__ float sUsum[544];                   // [b]*17 + z

    const int t  = threadIdx.x;
    const int jj = t & 15;        // this thread's j
    const int bb = t >> 4;        // 0..15; handles b-locals bb and bb+16
    const int bbase = blockIdx.x * TB;

    // bias -> LDS (512 floats)
    #pragma unroll
    for (int q = 0; q < 2; ++q) {
        int f = t + q * NTHREADS;
        sBias[(f >> 4) * 17 + (f & 15)] = Bias[f];
    }

    // x[b, jj, 0..7] -> registers, reused across all n and both passes
    float xr[2][8];
    #pragma unroll
    for (int r = 0; r < 2; ++r) {
        const float4* xp = reinterpret_cast<const float4*>(
            X + (size_t)(bbase + bb + 16 * r) * 128 + jj * 8);
        float4 a = xp[0];
        float4 c = xp[1];
        xr[r][0] = a.x; xr[r][1] = a.y; xr[r][2] = a.z; xr[r][3] = a.w;
        xr[r][4] = c.x; xr[r][5] = c.y; xr[r][6] = c.z; xr[r][7] = c.w;
    }

    // W[n] global->LDS staging addresses (coalesced float4 x2 per thread)
    const int wsrc = t * 2;              // float4 index within W[n] (2048 floats)
    const int wj   = t >> 4;             // dest j row
    const int wrem = (t & 15) * 8;       // offset within row
    float4* const wdst = reinterpret_cast<float4*>(&sW[wj * 132 + wrem]);

    // u[b, jj, z] for z=0..15, both b's; 8 FMA per ds_read_b128
    auto compute_u = [&](float (&u)[2][16]) {
        #pragma unroll
        for (int r = 0; r < 2; ++r)
            #pragma unroll
            for (int z = 0; z < 16; ++z) u[r][z] = 0.f;
        #pragma unroll
        for (int i = 0; i < 8; ++i) {
            const float4* wrow = reinterpret_cast<const float4*>(&sW[jj * 132 + i * 16]);
            float4 w0 = wrow[0], w1 = wrow[1], w2 = wrow[2], w3 = wrow[3];
            #pragma unroll
            for (int r = 0; r < 2; ++r) {
                const float xi = xr[r][i];
                u[r][0]  = fmaf(xi, w0.x, u[r][0]);  u[r][1]  = fmaf(xi, w0.y, u[r][1]);
                u[r][2]  = fmaf(xi, w0.z, u[r][2]);  u[r][3]  = fmaf(xi, w0.w, u[r][3]);
                u[r][4]  = fmaf(xi, w1.x, u[r][4]);  u[r][5]  = fmaf(xi, w1.y, u[r][5]);
                u[r][6]  = fmaf(xi, w1.z, u[r][6]);  u[r][7]  = fmaf(xi, w1.w, u[r][7]);
                u[r][8]  = fmaf(xi, w2.x, u[r][8]);  u[r][9]  = fmaf(xi, w2.y, u[r][9]);
                u[r][10] = fmaf(xi, w2.z, u[r][10]); u[r][11] = fmaf(xi, w2.w, u[r][11]);
                u[r][12] = fmaf(xi, w3.x, u[r][12]); u[r][13] = fmaf(xi, w3.y, u[r][13]);
                u[r][14] = fmaf(xi, w3.z, u[r][14]); u[r][15] = fmaf(xi, w3.w, u[r][15]);
            }
        }
    };

    auto store_u = [&](const float (&u)[2][16]) {
        #pragma unroll
        for (int r = 0; r < 2; ++r) {
            const int base = (bb + 16 * r) * 145 + jj * 9;
            #pragma unroll
            for (int zp = 0; zp < 8; ++zp) {
                unsigned int lo = f2bf(u[r][2 * zp]);
                unsigned int hi = f2bf(u[r][2 * zp + 1]);
                sU[base + zp] = lo | (hi << 16);
            }
        }
    };

    auto load_W = [&](int n) {
        const float4* wp = reinterpret_cast<const float4*>(W + (size_t)n * 2048);
        float4 w0 = wp[wsrc];
        float4 w1 = wp[wsrc + 1];
        wdst[0] = w0;
        wdst[1] = w1;
    };

    // ---------------- pass 1: logits for all n ----------------
    for (int n = 0; n < N_CAP; ++n) {
        __syncthreads();            // protect sW / sUsum from previous iteration readers
        load_W(n);
        __syncthreads();

        float u[2][16];
        compute_u(u);
        store_u(u);
        __syncthreads();

        // usum[b,z] = sum_j u[b,j,z]; thread (b2 = t>>3, z-pair = t&7)
        {
            const int b2 = t >> 3, zp2 = t & 7;
            float s0 = 0.f, s1 = 0.f;
            #pragma unroll
            for (int j = 0; j < 16; ++j) {
                unsigned int v = sU[b2 * 145 + j * 9 + zp2];
                s0 += bf2f(v & 0xffffu);
                s1 += bf2f(v >> 16);
            }
            sUsum[b2 * 17 + 2 * zp2]     = s0;
            sUsum[b2 * 17 + 2 * zp2 + 1] = s1;
        }
        __syncthreads();

        // logit[b,n,jj] = (u_jj . usum)/sqrt(D); u still in regs (fp32)
        #pragma unroll
        for (int r = 0; r < 2; ++r) {
            const int b = bb + 16 * r;
            float l = 0.f;
            #pragma unroll
            for (int z = 0; z < 16; ++z)
                l = fmaf(u[r][z], sUsum[b * 17 + z], l);
            l *= 0.25f;
            sC[b * 528 + n * 16 + jj] = f2bf(l);
        }
    }

    // ---------------- softmax over n (fully in-thread) ----------------
    #pragma unroll
    for (int r = 0; r < 2; ++r) {
        const int b = bb + 16 * r;
        float l[32];
        #pragma unroll
        for (int n = 0; n < 32; ++n) l[n] = bf2f((unsigned int)sC[b * 528 + n * 16 + jj]);
        float m = l[0];
        #pragma unroll
        for (int n = 1; n < 32; ++n) m = fmaxf(m, l[n]);
        float Z = 0.f;
        #pragma unroll
        for (int n = 0; n < 32; ++n) { l[n] = __expf(l[n] - m); Z += l[n]; }
        const float inv = 1.0f / Z;
        #pragma unroll
        for (int n = 0; n < 32; ++n)
            sC[b * 528 + n * 16 + jj] = f2bf(fmaf(l[n], inv, sBias[n * 17 + jj]));
    }

    // ---------------- pass 2: s[b,n,z] = sum_j c[b,n,j] * u[b,n,j,z] ----------------
    const int b2 = t >> 3, zp2 = t & 7;    // thread owns (b2, z-pair) for the s sum
    for (int n = 0; n < N_CAP; ++n) {
        __syncthreads();            // also orders softmax sC writes before first read
        load_W(n);
        __syncthreads();

        float u[2][16];
        compute_u(u);
        store_u(u);
        __syncthreads();

        float s0 = 0.f, s1 = 0.f;
        #pragma unroll
        for (int jp = 0; jp < 8; ++jp) {
            unsigned int cc = *reinterpret_cast<const unsigned int*>(
                &sC[b2 * 528 + n * 16 + 2 * jp]);
            float c0 = bf2f(cc & 0xffffu);
            float c1 = bf2f(cc >> 16);
            unsigned int ua = sU[b2 * 145 + (2 * jp) * 9 + zp2];
            unsigned int ub = sU[b2 * 145 + (2 * jp + 1) * 9 + zp2];
            s0 = fmaf(c0, bf2f(ua & 0xffffu), s0);
            s0 = fmaf(c1, bf2f(ub & 0xffffu), s0);
            s1 = fmaf(c0, bf2f(ua >> 16), s1);
            s1 = fmaf(c1, bf2f(ub >> 16), s1);
        }
        float2 o = make_float2(s0, s1);
        *reinterpret_cast<float2*>(Out + (size_t)(bbase + b2) * 512 + n * 16 + 2 * zp2) = o;
    }
}

extern "C" void kernel_launch(void* const* d_in, const int* in_sizes, int n_in,
                              void* d_out, int out_size, void* d_ws, size_t ws_size,
                              hipStream_t stream) {
    const float* X  = (const float*)d_in[0];   // (16384, 16, 8) fp32
    const float* W  = (const float*)d_in[1];   // (32, 16, 8, 16) fp32
    const float* Bi = (const float*)d_in[2];   // (32, 16, 1) fp32
    float* Out = (float*)d_out;                // (16384, 32, 16) fp32

    caps_fused<<<B_TOT / TB, NTHREADS, 0, stream>>>(X, W, Bi, Out);
}